// Round 11
// baseline (509.334 us; speedup 1.0000x reference)
//
#include <hip/hip_runtime.h>
#include <hip/hip_bf16.h>

#define NF 128   // feature dim
#define PB 512   // pool partial blocks
#define GEMM_BLOCKS 512  // persistent-ish gemm grid
#define PART_SHIFT 9     // 512 nodes per coarse bucket
#define PART_NODES 512
#define PART_CHUNK 4096  // edges per partition block (256 thr x 16)

typedef __attribute__((ext_vector_type(8))) short bf16x8;
typedef __attribute__((ext_vector_type(4))) float f32x4;

__device__ inline float b2f(ushort u) { return __uint_as_float(((uint)u) << 16); }
__device__ inline ushort f2bf(float f) {           // round-to-nearest-even
  uint u = __float_as_uint(f);
  return (ushort)((u + 0x7fffu + ((u >> 16) & 1u)) >> 16);
}
__device__ inline float blo(uint u) { return __uint_as_float(u << 16); }
__device__ inline float bhi(uint u) { return __uint_as_float(u & 0xffff0000u); }
__device__ inline uint bpack(float lo, float hi) {
  return (uint)f2bf(lo) | ((uint)f2bf(hi) << 16);
}

// ---------------- x -> bf16 ----------------
__global__ __launch_bounds__(256) void k_cvt(const float* __restrict__ x,
                                             ushort* __restrict__ xb, int total4) {
  for (int i = blockIdx.x * 256 + threadIdx.x; i < total4; i += gridDim.x * 256) {
    float4 v = *(const float4*)&x[(size_t)i * 4];
    ushort4 o;
    o.x = f2bf(v.x); o.y = f2bf(v.y); o.z = f2bf(v.z); o.w = f2bf(v.w);
    *(ushort4*)&xb[(size_t)i * 4] = o;
  }
}

// ---------------- weight prep: [k][c] f32 x2 -> [c][k 0..255] bf16 ----------------
__global__ __launch_bounds__(256) void k_wprep(const float* __restrict__ Wl1,
                                               const float* __restrict__ Wr1,
                                               const float* __restrict__ Wl2,
                                               const float* __restrict__ Wr2,
                                               const float* __restrict__ Wl3,
                                               const float* __restrict__ Wr3,
                                               ushort* __restrict__ Wtg) {
  int l = blockIdx.x >> 7;          // layer 0..2
  int c = blockIdx.x & 127;         // col
  int k = threadIdx.x;              // 0..255
  const float* Wl = (l == 0) ? Wl1 : (l == 1) ? Wl2 : Wl3;
  const float* Wr = (l == 0) ? Wr1 : (l == 1) ? Wr2 : Wr3;
  float v = (k < 128) ? Wl[k * NF + c] : Wr[(k - 128) * NF + c];
  Wtg[((size_t)l * NF + c) * 256 + k] = f2bf(v);
}

// ---------------- CSR build (atomic-free, chunk x bucket) ----------------
__global__ __launch_bounds__(256) void k_part1(const int* __restrict__ dst,
                                               int* __restrict__ bcnt, int E) {
  __shared__ int lhist[256];
  int t = threadIdx.x;
  int cb = blockIdx.x * PART_CHUNK;
  lhist[t] = 0;
  __syncthreads();
  #pragma unroll
  for (int i = 0; i < 16; i++) {
    int e = cb + i * 256 + t;
    if (e < E) atomicAdd(&lhist[dst[e] >> PART_SHIFT], 1);
  }
  __syncthreads();
  bcnt[blockIdx.x * 256 + t] = lhist[t];
}

// per-bucket column scan over chunks (256 blocks, parallel)
__global__ __launch_bounds__(256) void k_bscan1(const int* __restrict__ bcnt,
                                                int* __restrict__ cbase,
                                                int* __restrict__ btot, int npart) {
  __shared__ int s[256];
  int b = blockIdx.x;   // bucket
  int t = threadIdx.x;
  int base = 0;
  for (int seg = 0; seg * 256 < npart; seg++) {
    int c = seg * 256 + t;
    int v = (c < npart) ? bcnt[c * 256 + b] : 0;
    s[t] = v;
    __syncthreads();
    for (int off = 1; off < 256; off <<= 1) {
      int u = (t >= off) ? s[t - off] : 0;
      __syncthreads();
      s[t] += u;
      __syncthreads();
    }
    if (c < npart) cbase[c * 256 + b] = base + s[t] - v;  // chunk-exclusive, no bucket base
    base += s[255];
    __syncthreads();
  }
  if (t == 0) btot[b] = base;
}

// 1 block: bucket_start[0..256], row_start[n]=E
__global__ __launch_bounds__(256) void k_bscan2(const int* __restrict__ btot,
                                                int* __restrict__ bucket_start,
                                                int* __restrict__ row_start,
                                                int n, int E) {
  __shared__ int s[256];
  int t = threadIdx.x;
  int v = btot[t];
  s[t] = v;
  __syncthreads();
  for (int off = 1; off < 256; off <<= 1) {
    int u = (t >= off) ? s[t - off] : 0;
    __syncthreads();
    s[t] += u;
    __syncthreads();
  }
  bucket_start[t] = s[t] - v;            // exclusive prefix
  if (t == 255) bucket_start[256] = s[255];   // = E
  if (t == 0) row_start[n] = E;
}

// LDS-ranked scatter into reserved runs (no global atomics)
__global__ __launch_bounds__(256) void k_part2(const int* __restrict__ src,
                                               const int* __restrict__ dst,
                                               const int* __restrict__ cbase,
                                               const int* __restrict__ bucket_start,
                                               uint* __restrict__ bkt, int E) {
  __shared__ int lhist[256];
  __shared__ int lbase[256];
  int t = threadIdx.x;
  int cb = blockIdx.x * PART_CHUNK;
  lhist[t] = 0;
  __syncthreads();
  uint rec[16];
  short rb[16];
  short rr[16];
  #pragma unroll
  for (int i = 0; i < 16; i++) {
    int e = cb + i * 256 + t;
    if (e < E) {
      int s = src[e], d = dst[e];
      int b = d >> PART_SHIFT;
      rec[i] = ((uint)(d & (PART_NODES - 1)) << 17) | (uint)s;
      rb[i] = (short)b;
      rr[i] = (short)atomicAdd(&lhist[b], 1);
    } else rb[i] = -1;
  }
  __syncthreads();
  lbase[t] = cbase[blockIdx.x * 256 + t] + bucket_start[t];
  __syncthreads();
  #pragma unroll
  for (int i = 0; i < 16; i++) {
    if (rb[i] >= 0) bkt[lbase[rb[i]] + (int)rr[i]] = rec[i];
  }
}

// one block per bucket; LDS degree count + scan -> row_start + place col
__global__ __launch_bounds__(256) void k_fill4(const uint* __restrict__ bkt,
                                               const int* __restrict__ bucket_start,
                                               int* __restrict__ row_start,
                                               int* __restrict__ col, int n) {
  __shared__ int dcnt[PART_NODES];
  __shared__ int s[256];
  __shared__ int cur[PART_NODES];
  int t = threadIdx.x;
  int base = blockIdx.x << PART_SHIFT;
  dcnt[2 * t] = 0; dcnt[2 * t + 1] = 0;
  __syncthreads();
  int ebeg = bucket_start[blockIdx.x], eend = bucket_start[blockIdx.x + 1];
  for (int j = ebeg + t; j < eend; j += 256)
    atomicAdd(&dcnt[bkt[j] >> 17], 1);
  __syncthreads();
  int d0 = dcnt[2 * t], d1 = dcnt[2 * t + 1];
  int pair = d0 + d1;
  s[t] = pair;
  __syncthreads();
  for (int off = 1; off < 256; off <<= 1) {
    int u = (t >= off) ? s[t - off] : 0;
    __syncthreads();
    s[t] += u;
    __syncthreads();
  }
  int pre = ebeg + s[t] - pair;      // exclusive within bucket
  cur[2 * t] = pre;
  cur[2 * t + 1] = pre + d0;
  if (base + 2 * t < n)     row_start[base + 2 * t]     = pre;
  if (base + 2 * t + 1 < n) row_start[base + 2 * t + 1] = pre + d0;
  __syncthreads();
  for (int j = ebeg + t; j < eend; j += 256) {
    uint r = bkt[j];
    int pos = atomicAdd(&cur[r >> 17], 1);
    col[pos] = (int)(r & 0x1FFFFu);
  }
}

// ---------------- gather-mean (bf16 in/out, fp32 accum) ----------------
// one wave per node; quarter-split: quarter q (lane>>4) handles edges 4i+q,
// each lane owns 8 feats (16B uint4 loads -> 4 rows / 1KB per instruction
// across the wave); col indices prefetched 64-at-a-time, broadcast via shfl;
// 16 edges in flight (~4KB/wave outstanding).
__global__ __launch_bounds__(256) void k_aggr_bf(const ushort* __restrict__ h,
                                                 const int* __restrict__ row_start,
                                                 const int* __restrict__ col,
                                                 ushort* __restrict__ aggr, int n) {
  int gw = (blockIdx.x * 256 + threadIdx.x) >> 6;
  int lane = threadIdx.x & 63;
  if (gw >= n) return;
  int beg = row_start[gw], end = row_start[gw + 1];
  int q = lane >> 4, sl = lane & 15;
  const ushort* hbase = h + (size_t)sl * 8;
  float a0 = 0.f, a1 = 0.f, a2 = 0.f, a3 = 0.f;
  float a4 = 0.f, a5 = 0.f, a6 = 0.f, a7 = 0.f;

  for (int cb = beg; cb < end; cb += 64) {
    int idx = cb + lane;
    int cv = (idx < end) ? col[idx] : 0;
    int m = min(64, end - cb);
    int j = 0;
    for (; j + 16 <= m; j += 16) {       // 4 quads (16 edges) in flight
      int s0 = __shfl(cv, j + q);
      int s1 = __shfl(cv, j + 4 + q);
      int s2 = __shfl(cv, j + 8 + q);
      int s3 = __shfl(cv, j + 12 + q);
      uint4 v0 = *(const uint4*)&hbase[(size_t)s0 * NF];
      uint4 v1 = *(const uint4*)&hbase[(size_t)s1 * NF];
      uint4 v2 = *(const uint4*)&hbase[(size_t)s2 * NF];
      uint4 v3 = *(const uint4*)&hbase[(size_t)s3 * NF];
      a0 += blo(v0.x) + blo(v1.x) + blo(v2.x) + blo(v3.x);
      a1 += bhi(v0.x) + bhi(v1.x) + bhi(v2.x) + bhi(v3.x);
      a2 += blo(v0.y) + blo(v1.y) + blo(v2.y) + blo(v3.y);
      a3 += bhi(v0.y) + bhi(v1.y) + bhi(v2.y) + bhi(v3.y);
      a4 += blo(v0.z) + blo(v1.z) + blo(v2.z) + blo(v3.z);
      a5 += bhi(v0.z) + bhi(v1.z) + bhi(v2.z) + bhi(v3.z);
      a6 += blo(v0.w) + blo(v1.w) + blo(v2.w) + blo(v3.w);
      a7 += bhi(v0.w) + bhi(v1.w) + bhi(v2.w) + bhi(v3.w);
    }
    for (; j < m; j += 4) {              // tail quads (possibly partial)
      int e = j + q;
      int s = __shfl(cv, (e < m) ? e : 0);
      if (e < m) {
        uint4 v = *(const uint4*)&hbase[(size_t)s * NF];
        a0 += blo(v.x); a1 += bhi(v.x);
        a2 += blo(v.y); a3 += bhi(v.y);
        a4 += blo(v.z); a5 += bhi(v.z);
        a6 += blo(v.w); a7 += bhi(v.w);
      }
    }
  }
  // combine the four quarters (feats identical, edge subsets disjoint)
  a0 += __shfl_xor(a0, 16); a0 += __shfl_xor(a0, 32);
  a1 += __shfl_xor(a1, 16); a1 += __shfl_xor(a1, 32);
  a2 += __shfl_xor(a2, 16); a2 += __shfl_xor(a2, 32);
  a3 += __shfl_xor(a3, 16); a3 += __shfl_xor(a3, 32);
  a4 += __shfl_xor(a4, 16); a4 += __shfl_xor(a4, 32);
  a5 += __shfl_xor(a5, 16); a5 += __shfl_xor(a5, 32);
  a6 += __shfl_xor(a6, 16); a6 += __shfl_xor(a6, 32);
  a7 += __shfl_xor(a7, 16); a7 += __shfl_xor(a7, 32);
  int d = end - beg;
  float inv = (d > 0) ? 1.0f / (float)d : 0.0f;
  if (q == 0) {
    uint4 o;
    o.x = bpack(a0 * inv, a1 * inv);
    o.y = bpack(a2 * inv, a3 * inv);
    o.z = bpack(a4 * inv, a5 * inv);
    o.w = bpack(a6 * inv, a7 * inv);
    *(uint4*)&aggr[(size_t)gw * NF + sl * 8] = o;
  }
}

// ---------------- MFMA GEMM (no LDS): hout = relu([aggr|hin] @ Wtg_l + b) ----------------
// B-frags loaded straight from pre-transposed global weights (L2-hot, 256B/thread).
__global__ __launch_bounds__(256) void k_gemm_mfma(const ushort* __restrict__ aggr,
                                                   const ushort* __restrict__ hin,
                                                   ushort* __restrict__ hout,
                                                   const ushort* __restrict__ Wtg,
                                                   const float* __restrict__ bias,
                                                   int n, int nslab) {
  int t = threadIdx.x;
  int wv = t >> 6, lane = t & 63;
  int c0 = wv * 32;
  int lrow = lane & 15, lhi = lane >> 4;

  // lane holds B[k = kc*32 + lhi*8 + j][col = c0 + ct*16 + lrow]
  bf16x8 bfrag[8][2];
  #pragma unroll
  for (int kc = 0; kc < 8; kc++)
    #pragma unroll
    for (int ct = 0; ct < 2; ct++) {
      int colv = c0 + ct * 16 + lrow;
      bfrag[kc][ct] = *(const bf16x8*)&Wtg[(size_t)colv * 256 + kc * 32 + lhi * 8];
    }
  float bv0 = bias[c0 + lrow], bv1 = bias[c0 + 16 + lrow];

  for (int sl = blockIdx.x; sl < nslab; sl += GEMM_BLOCKS) {
    int row0 = sl * 64;
    f32x4 acc[4][2];
    #pragma unroll
    for (int rt = 0; rt < 4; rt++)
      #pragma unroll
      for (int ct = 0; ct < 2; ct++) acc[rt][ct] = (f32x4){0.f, 0.f, 0.f, 0.f};

    #pragma unroll
    for (int kc = 0; kc < 8; kc++) {
      const ushort* Asrc = (kc < 4) ? aggr : hin;
      int k0 = (kc & 3) * 32 + lhi * 8;
      bf16x8 af[4];
      #pragma unroll
      for (int rt = 0; rt < 4; rt++) {
        int r = row0 + rt * 16 + lrow;
        if (r >= n) r = n - 1;
        af[rt] = *(const bf16x8*)&Asrc[(size_t)r * NF + k0];
      }
      #pragma unroll
      for (int rt = 0; rt < 4; rt++) {
        acc[rt][0] = __builtin_amdgcn_mfma_f32_16x16x32_bf16(af[rt], bfrag[kc][0], acc[rt][0], 0, 0, 0);
        acc[rt][1] = __builtin_amdgcn_mfma_f32_16x16x32_bf16(af[rt], bfrag[kc][1], acc[rt][1], 0, 0, 0);
      }
    }
    // C/D: col = lane&15, row = (lane>>4)*4 + reg   [m89-verified]
    #pragma unroll
    for (int rt = 0; rt < 4; rt++) {
      int rbase = row0 + rt * 16 + lhi * 4;
      #pragma unroll
      for (int r = 0; r < 4; r++) {
        int row = rbase + r;
        if (row < n) {
          hout[(size_t)row * NF + c0 + lrow]      = f2bf(fmaxf(acc[rt][0][r] + bv0, 0.f));
          hout[(size_t)row * NF + c0 + 16 + lrow] = f2bf(fmaxf(acc[rt][1][r] + bv1, 0.f));
        }
      }
    }
  }
}

// ---------------- pool + head ----------------
__global__ __launch_bounds__(128) void k_pool1(const ushort* __restrict__ h,
                                               float* __restrict__ partial, int n) {
  int f = threadIdx.x;
  float s = 0.f;
  for (int r = blockIdx.x; r < n; r += PB) s += b2f(h[(size_t)r * NF + f]);
  partial[blockIdx.x * NF + f] = s;
}

__global__ __launch_bounds__(128) void k_pool2(const float* __restrict__ partial,
                                               const float* __restrict__ Wg,
                                               const float* __restrict__ bg,
                                               float* __restrict__ out, int n) {
  __shared__ float g[NF];
  int f = threadIdx.x;
  float s = 0.f;
  for (int b = 0; b < PB; b++) s += partial[b * NF + f];
  g[f] = s / (float)n;
  __syncthreads();
  if (f < 64) {
    float z = bg[f];
    #pragma unroll 4
    for (int k = 0; k < NF; k++) z += g[k] * Wg[k * 64 + f];
    out[f] = 1.0f / (1.0f + expf(-z));
  }
}

// ---------------- launch ----------------
extern "C" void kernel_launch(void* const* d_in, const int* in_sizes, int n_in,
                              void* d_out, int out_size, void* d_ws, size_t ws_size,
                              hipStream_t stream) {
  const float* x   = (const float*)d_in[0];
  const int*   ei  = (const int*)d_in[1];
  const float* Wl1 = (const float*)d_in[2];
  const float* Wr1 = (const float*)d_in[3];
  const float* b1  = (const float*)d_in[4];
  const float* Wl2 = (const float*)d_in[5];
  const float* Wr2 = (const float*)d_in[6];
  const float* b2  = (const float*)d_in[7];
  const float* Wl3 = (const float*)d_in[8];
  const float* Wr3 = (const float*)d_in[9];
  const float* b3  = (const float*)d_in[10];
  const float* Wg  = (const float*)d_in[11];
  const float* bg  = (const float*)d_in[12];
  float* out = (float*)d_out;

  int n = in_sizes[0] / NF;      // 100000
  int E = in_sizes[1] / 2;       // 1600000
  const int* srcp = ei;
  const int* dstp = ei + E;

  char* w = (char*)d_ws;
  size_t off = 0;
  auto carve = [&](size_t bytes) -> void* {
    off = (off + 255) & ~(size_t)255;
    void* p = w + off;
    off += bytes;
    return p;
  };
  int nbkt  = (n + PART_NODES - 1) / PART_NODES;   // 196 coarse buckets
  int npart = (E + PART_CHUNK - 1) / PART_CHUNK;   // 391 chunks
  int*    col       = (int*)   carve((size_t)E * 4);
  int*    row_start = (int*)   carve((size_t)(n + 1) * 4);
  int*    bucket_start = (int*)carve((size_t)257 * 4);
  int*    btot      = (int*)   carve((size_t)256 * 4);
  int*    bcnt      = (int*)   carve((size_t)npart * 256 * 4);
  int*    cbase     = (int*)   carve((size_t)npart * 256 * 4);
  ushort* Wtg       = (ushort*)carve((size_t)3 * NF * 256 * 2);
  ushort* xb        = (ushort*)carve((size_t)n * NF * 2);
  ushort* aggr      = (ushort*)carve((size_t)n * NF * 2);
  ushort* ha        = (ushort*)carve((size_t)n * NF * 2);
  ushort* hb        = (ushort*)carve((size_t)n * NF * 2);
  float*  partial   = (float*) carve((size_t)PB * NF * 4);
  uint*   bkt       = (uint*)hb;   // 4B-packed staging aliases hb (dead until layer 2)

  int ag = (n + 3) / 4;
  int nslab = (n + 63) / 64;

  // convert x to bf16; prep transposed bf16 weights
  k_cvt<<<2048, 256, 0, stream>>>(x, xb, n * NF / 4);
  k_wprep<<<3 * NF, 256, 0, stream>>>(Wl1, Wr1, Wl2, Wr2, Wl3, Wr3, Wtg);

  // CSR build: chunk-histogram -> parallel 2D scan -> reserved scatter -> bucket-local fill
  k_part1<<<npart, 256, 0, stream>>>(dstp, bcnt, E);
  k_bscan1<<<256, 256, 0, stream>>>(bcnt, cbase, btot, npart);
  k_bscan2<<<1, 256, 0, stream>>>(btot, bucket_start, row_start, n, E);
  k_part2<<<npart, 256, 0, stream>>>(srcp, dstp, cbase, bucket_start, bkt, E);
  k_fill4<<<nbkt, 256, 0, stream>>>(bkt, bucket_start, row_start, col, n);

  // layer 1: xb -> ha
  k_aggr_bf<<<ag, 256, 0, stream>>>(xb, row_start, col, aggr, n);
  k_gemm_mfma<<<GEMM_BLOCKS, 256, 0, stream>>>(aggr, xb, ha, Wtg,            b1, n, nslab);
  // layer 2: ha -> hb
  k_aggr_bf<<<ag, 256, 0, stream>>>(ha, row_start, col, aggr, n);
  k_gemm_mfma<<<GEMM_BLOCKS, 256, 0, stream>>>(aggr, ha, hb, Wtg + NF * 256, b2, n, nslab);
  // layer 3: hb -> ha
  k_aggr_bf<<<ag, 256, 0, stream>>>(hb, row_start, col, aggr, n);
  k_gemm_mfma<<<GEMM_BLOCKS, 256, 0, stream>>>(aggr, hb, ha, Wtg + 2 * NF * 256, b3, n, nslab);

  // pool + head
  k_pool1<<<PB, 128, 0, stream>>>(ha, partial, n);
  k_pool2<<<1, 128, 0, stream>>>(partial, Wg, bg, out, n);
}

// Round 12
// 485.144 us; speedup vs baseline: 1.0499x; 1.0499x over previous
//
#include <hip/hip_runtime.h>
#include <hip/hip_bf16.h>

#define NF 128   // feature dim
#define PB 512   // pool partial blocks
#define GEMM_BLOCKS 512  // persistent-ish gemm grid
#define PART_SHIFT 9     // 512 nodes per coarse bucket
#define PART_NODES 512
#define PART_CHUNK 4096  // edges per partition block (256 thr x 16)

typedef __attribute__((ext_vector_type(8))) short bf16x8;
typedef __attribute__((ext_vector_type(4))) float f32x4;
typedef __attribute__((ext_vector_type(2))) float f32x2;

__device__ inline float b2f(ushort u) { return __uint_as_float(((uint)u) << 16); }
__device__ inline ushort f2bf(float f) {           // round-to-nearest-even
  uint u = __float_as_uint(f);
  return (ushort)((u + 0x7fffu + ((u >> 16) & 1u)) >> 16);
}

// fp8 e4m3 (OCP) pack/unpack via HW converts
__device__ inline uint pk8(float a, float b) {     // 2 floats -> 2 fp8 bytes [b:a]
  return (uint)__builtin_amdgcn_cvt_pk_fp8_f32(a, b, 0, false);
}

// ---------------- x -> bf16 + fp8 ----------------
__global__ __launch_bounds__(256) void k_cvt(const float* __restrict__ x,
                                             ushort* __restrict__ xb,
                                             uchar* __restrict__ x8, int total4) {
  for (int i = blockIdx.x * 256 + threadIdx.x; i < total4; i += gridDim.x * 256) {
    float4 v = *(const float4*)&x[(size_t)i * 4];
    ushort4 o;
    o.x = f2bf(v.x); o.y = f2bf(v.y); o.z = f2bf(v.z); o.w = f2bf(v.w);
    *(ushort4*)&xb[(size_t)i * 4] = o;
    int p = __builtin_amdgcn_cvt_pk_fp8_f32(v.x, v.y, 0, false);
    p = __builtin_amdgcn_cvt_pk_fp8_f32(v.z, v.w, p, true);
    *(uint*)&x8[(size_t)i * 4] = (uint)p;
  }
}

// ---------------- weight prep: [k][c] f32 x2 -> [c][k 0..255] bf16 ----------------
__global__ __launch_bounds__(256) void k_wprep(const float* __restrict__ Wl1,
                                               const float* __restrict__ Wr1,
                                               const float* __restrict__ Wl2,
                                               const float* __restrict__ Wr2,
                                               const float* __restrict__ Wl3,
                                               const float* __restrict__ Wr3,
                                               ushort* __restrict__ Wtg) {
  int l = blockIdx.x >> 7;          // layer 0..2
  int c = blockIdx.x & 127;         // col
  int k = threadIdx.x;              // 0..255
  const float* Wl = (l == 0) ? Wl1 : (l == 1) ? Wl2 : Wl3;
  const float* Wr = (l == 0) ? Wr1 : (l == 1) ? Wr2 : Wr3;
  float v = (k < 128) ? Wl[k * NF + c] : Wr[(k - 128) * NF + c];
  Wtg[((size_t)l * NF + c) * 256 + k] = f2bf(v);
}

// ---------------- CSR build (atomic-free, chunk x bucket) ----------------
__global__ __launch_bounds__(256) void k_part1(const int* __restrict__ dst,
                                               int* __restrict__ bcnt, int E) {
  __shared__ int lhist[256];
  int t = threadIdx.x;
  int cb = blockIdx.x * PART_CHUNK;
  lhist[t] = 0;
  __syncthreads();
  #pragma unroll
  for (int i = 0; i < 16; i++) {
    int e = cb + i * 256 + t;
    if (e < E) atomicAdd(&lhist[dst[e] >> PART_SHIFT], 1);
  }
  __syncthreads();
  bcnt[blockIdx.x * 256 + t] = lhist[t];
}

// per-bucket column scan over chunks (256 blocks, parallel)
__global__ __launch_bounds__(256) void k_bscan1(const int* __restrict__ bcnt,
                                                int* __restrict__ cbase,
                                                int* __restrict__ btot, int npart) {
  __shared__ int s[256];
  int b = blockIdx.x;   // bucket
  int t = threadIdx.x;
  int base = 0;
  for (int seg = 0; seg * 256 < npart; seg++) {
    int c = seg * 256 + t;
    int v = (c < npart) ? bcnt[c * 256 + b] : 0;
    s[t] = v;
    __syncthreads();
    for (int off = 1; off < 256; off <<= 1) {
      int u = (t >= off) ? s[t - off] : 0;
      __syncthreads();
      s[t] += u;
      __syncthreads();
    }
    if (c < npart) cbase[c * 256 + b] = base + s[t] - v;  // chunk-exclusive, no bucket base
    base += s[255];
    __syncthreads();
  }
  if (t == 0) btot[b] = base;
}

// 1 block: bucket_start[0..256], row_start[n]=E
__global__ __launch_bounds__(256) void k_bscan2(const int* __restrict__ btot,
                                                int* __restrict__ bucket_start,
                                                int* __restrict__ row_start,
                                                int n, int E) {
  __shared__ int s[256];
  int t = threadIdx.x;
  int v = btot[t];
  s[t] = v;
  __syncthreads();
  for (int off = 1; off < 256; off <<= 1) {
    int u = (t >= off) ? s[t - off] : 0;
    __syncthreads();
    s[t] += u;
    __syncthreads();
  }
  bucket_start[t] = s[t] - v;            // exclusive prefix
  if (t == 255) bucket_start[256] = s[255];   // = E
  if (t == 0) row_start[n] = E;
}

// LDS-ranked scatter into reserved runs (no global atomics)
__global__ __launch_bounds__(256) void k_part2(const int* __restrict__ src,
                                               const int* __restrict__ dst,
                                               const int* __restrict__ cbase,
                                               const int* __restrict__ bucket_start,
                                               uint* __restrict__ bkt, int E) {
  __shared__ int lhist[256];
  __shared__ int lbase[256];
  int t = threadIdx.x;
  int cb = blockIdx.x * PART_CHUNK;
  lhist[t] = 0;
  __syncthreads();
  uint rec[16];
  short rb[16];
  short rr[16];
  #pragma unroll
  for (int i = 0; i < 16; i++) {
    int e = cb + i * 256 + t;
    if (e < E) {
      int s = src[e], d = dst[e];
      int b = d >> PART_SHIFT;
      rec[i] = ((uint)(d & (PART_NODES - 1)) << 17) | (uint)s;
      rb[i] = (short)b;
      rr[i] = (short)atomicAdd(&lhist[b], 1);
    } else rb[i] = -1;
  }
  __syncthreads();
  lbase[t] = cbase[blockIdx.x * 256 + t] + bucket_start[t];
  __syncthreads();
  #pragma unroll
  for (int i = 0; i < 16; i++) {
    if (rb[i] >= 0) bkt[lbase[rb[i]] + (int)rr[i]] = rec[i];
  }
}

// one block per bucket; LDS degree count + scan -> row_start + place col
__global__ __launch_bounds__(256) void k_fill4(const uint* __restrict__ bkt,
                                               const int* __restrict__ bucket_start,
                                               int* __restrict__ row_start,
                                               int* __restrict__ col, int n) {
  __shared__ int dcnt[PART_NODES];
  __shared__ int s[256];
  __shared__ int cur[PART_NODES];
  int t = threadIdx.x;
  int base = blockIdx.x << PART_SHIFT;
  dcnt[2 * t] = 0; dcnt[2 * t + 1] = 0;
  __syncthreads();
  int ebeg = bucket_start[blockIdx.x], eend = bucket_start[blockIdx.x + 1];
  for (int j = ebeg + t; j < eend; j += 256)
    atomicAdd(&dcnt[bkt[j] >> 17], 1);
  __syncthreads();
  int d0 = dcnt[2 * t], d1 = dcnt[2 * t + 1];
  int pair = d0 + d1;
  s[t] = pair;
  __syncthreads();
  for (int off = 1; off < 256; off <<= 1) {
    int u = (t >= off) ? s[t - off] : 0;
    __syncthreads();
    s[t] += u;
    __syncthreads();
  }
  int pre = ebeg + s[t] - pair;      // exclusive within bucket
  cur[2 * t] = pre;
  cur[2 * t + 1] = pre + d0;
  if (base + 2 * t < n)     row_start[base + 2 * t]     = pre;
  if (base + 2 * t + 1 < n) row_start[base + 2 * t + 1] = pre + d0;
  __syncthreads();
  for (int j = ebeg + t; j < eend; j += 256) {
    uint r = bkt[j];
    int pos = atomicAdd(&cur[r >> 17], 1);
    col[pos] = (int)(r & 0x1FFFFu);
  }
}

// ---------------- gather-mean (fp8 in, bf16 out, fp32 accum) ----------------
// one wave per node; quarter-split: quarter q handles edges 4i+q, each lane
// owns 8 feats (8B uint2 loads; fp8 row = 128B = ONE cache line); col indices
// prefetched 64-at-a-time, broadcast via shfl; 16 edges in flight.
__global__ __launch_bounds__(256) void k_aggr_bf(const uchar* __restrict__ h8,
                                                 const int* __restrict__ row_start,
                                                 const int* __restrict__ col,
                                                 ushort* __restrict__ aggr, int n) {
  int gw = (blockIdx.x * 256 + threadIdx.x) >> 6;
  int lane = threadIdx.x & 63;
  if (gw >= n) return;
  int beg = row_start[gw], end = row_start[gw + 1];
  int q = lane >> 4, sl = lane & 15;
  const uchar* hbase = h8 + (size_t)sl * 8;
  float a[8];
  #pragma unroll
  for (int i = 0; i < 8; i++) a[i] = 0.f;

  for (int cb = beg; cb < end; cb += 64) {
    int idx = cb + lane;
    int cv = (idx < end) ? col[idx] : 0;
    int m = min(64, end - cb);
    int j = 0;
    for (; j + 16 <= m; j += 16) {       // 4 quads (16 edges) in flight
      int s0 = __shfl(cv, j + q);
      int s1 = __shfl(cv, j + 4 + q);
      int s2 = __shfl(cv, j + 8 + q);
      int s3 = __shfl(cv, j + 12 + q);
      uint2 v0 = *(const uint2*)&hbase[(size_t)s0 * NF];
      uint2 v1 = *(const uint2*)&hbase[(size_t)s1 * NF];
      uint2 v2 = *(const uint2*)&hbase[(size_t)s2 * NF];
      uint2 v3 = *(const uint2*)&hbase[(size_t)s3 * NF];
      #pragma unroll
      for (int k = 0; k < 4; k++) {
        uint2 v = (k == 0) ? v0 : (k == 1) ? v1 : (k == 2) ? v2 : v3;
        f32x2 f0 = __builtin_amdgcn_cvt_pk_f32_fp8((int)v.x, false);
        f32x2 f1 = __builtin_amdgcn_cvt_pk_f32_fp8((int)v.x, true);
        f32x2 f2 = __builtin_amdgcn_cvt_pk_f32_fp8((int)v.y, false);
        f32x2 f3 = __builtin_amdgcn_cvt_pk_f32_fp8((int)v.y, true);
        a[0] += f0.x; a[1] += f0.y; a[2] += f1.x; a[3] += f1.y;
        a[4] += f2.x; a[5] += f2.y; a[6] += f3.x; a[7] += f3.y;
      }
    }
    for (; j < m; j += 4) {              // tail quads (possibly partial)
      int e = j + q;
      int s = __shfl(cv, (e < m) ? e : 0);
      if (e < m) {
        uint2 v = *(const uint2*)&hbase[(size_t)s * NF];
        f32x2 f0 = __builtin_amdgcn_cvt_pk_f32_fp8((int)v.x, false);
        f32x2 f1 = __builtin_amdgcn_cvt_pk_f32_fp8((int)v.x, true);
        f32x2 f2 = __builtin_amdgcn_cvt_pk_f32_fp8((int)v.y, false);
        f32x2 f3 = __builtin_amdgcn_cvt_pk_f32_fp8((int)v.y, true);
        a[0] += f0.x; a[1] += f0.y; a[2] += f1.x; a[3] += f1.y;
        a[4] += f2.x; a[5] += f2.y; a[6] += f3.x; a[7] += f3.y;
      }
    }
  }
  // combine the four quarters (feats identical, edge subsets disjoint)
  #pragma unroll
  for (int i = 0; i < 8; i++) {
    a[i] += __shfl_xor(a[i], 16);
    a[i] += __shfl_xor(a[i], 32);
  }
  int d = end - beg;
  float inv = (d > 0) ? 1.0f / (float)d : 0.0f;
  if (q == 0) {
    uint4 o;
    o.x = (uint)f2bf(a[0] * inv) | ((uint)f2bf(a[1] * inv) << 16);
    o.y = (uint)f2bf(a[2] * inv) | ((uint)f2bf(a[3] * inv) << 16);
    o.z = (uint)f2bf(a[4] * inv) | ((uint)f2bf(a[5] * inv) << 16);
    o.w = (uint)f2bf(a[6] * inv) | ((uint)f2bf(a[7] * inv) << 16);
    *(uint4*)&aggr[(size_t)gw * NF + sl * 8] = o;
  }
}

// ---------------- MFMA GEMM (no LDS): hout = relu([aggr|hin] @ Wtg_l + b) ----------------
// also emits fp8 shadow copy h8out for the next layer's gather.
__global__ __launch_bounds__(256) void k_gemm_mfma(const ushort* __restrict__ aggr,
                                                   const ushort* __restrict__ hin,
                                                   ushort* __restrict__ hout,
                                                   uchar* __restrict__ h8out,
                                                   const ushort* __restrict__ Wtg,
                                                   const float* __restrict__ bias,
                                                   int n, int nslab) {
  int t = threadIdx.x;
  int wv = t >> 6, lane = t & 63;
  int c0 = wv * 32;
  int lrow = lane & 15, lhi = lane >> 4;

  // lane holds B[k = kc*32 + lhi*8 + j][col = c0 + ct*16 + lrow]
  bf16x8 bfrag[8][2];
  #pragma unroll
  for (int kc = 0; kc < 8; kc++)
    #pragma unroll
    for (int ct = 0; ct < 2; ct++) {
      int colv = c0 + ct * 16 + lrow;
      bfrag[kc][ct] = *(const bf16x8*)&Wtg[(size_t)colv * 256 + kc * 32 + lhi * 8];
    }
  float bv0 = bias[c0 + lrow], bv1 = bias[c0 + 16 + lrow];

  for (int sl = blockIdx.x; sl < nslab; sl += GEMM_BLOCKS) {
    int row0 = sl * 64;
    f32x4 acc[4][2];
    #pragma unroll
    for (int rt = 0; rt < 4; rt++)
      #pragma unroll
      for (int ct = 0; ct < 2; ct++) acc[rt][ct] = (f32x4){0.f, 0.f, 0.f, 0.f};

    #pragma unroll
    for (int kc = 0; kc < 8; kc++) {
      const ushort* Asrc = (kc < 4) ? aggr : hin;
      int k0 = (kc & 3) * 32 + lhi * 8;
      bf16x8 af[4];
      #pragma unroll
      for (int rt = 0; rt < 4; rt++) {
        int r = row0 + rt * 16 + lrow;
        if (r >= n) r = n - 1;
        af[rt] = *(const bf16x8*)&Asrc[(size_t)r * NF + k0];
      }
      #pragma unroll
      for (int rt = 0; rt < 4; rt++) {
        acc[rt][0] = __builtin_amdgcn_mfma_f32_16x16x32_bf16(af[rt], bfrag[kc][0], acc[rt][0], 0, 0, 0);
        acc[rt][1] = __builtin_amdgcn_mfma_f32_16x16x32_bf16(af[rt], bfrag[kc][1], acc[rt][1], 0, 0, 0);
      }
    }
    // C/D: col = lane&15, row = (lane>>4)*4 + reg   [m89-verified]
    #pragma unroll
    for (int rt = 0; rt < 4; rt++) {
      int rbase = row0 + rt * 16 + lhi * 4;
      #pragma unroll
      for (int r = 0; r < 4; r++) {
        int row = rbase + r;
        if (row < n) {
          float o0 = fmaxf(acc[rt][0][r] + bv0, 0.f);
          float o1 = fmaxf(acc[rt][1][r] + bv1, 0.f);
          hout[(size_t)row * NF + c0 + lrow]      = f2bf(o0);
          hout[(size_t)row * NF + c0 + 16 + lrow] = f2bf(o1);
          uint p = pk8(o0, o1);
          h8out[(size_t)row * NF + c0 + lrow]      = (uchar)(p & 0xff);
          h8out[(size_t)row * NF + c0 + 16 + lrow] = (uchar)((p >> 8) & 0xff);
        }
      }
    }
  }
}

// ---------------- pool + head ----------------
__global__ __launch_bounds__(128) void k_pool1(const ushort* __restrict__ h,
                                               float* __restrict__ partial, int n) {
  int f = threadIdx.x;
  float s = 0.f;
  for (int r = blockIdx.x; r < n; r += PB) s += b2f(h[(size_t)r * NF + f]);
  partial[blockIdx.x * NF + f] = s;
}

__global__ __launch_bounds__(128) void k_pool2(const float* __restrict__ partial,
                                               const float* __restrict__ Wg,
                                               const float* __restrict__ bg,
                                               float* __restrict__ out, int n) {
  __shared__ float g[NF];
  int f = threadIdx.x;
  float s = 0.f;
  for (int b = 0; b < PB; b++) s += partial[b * NF + f];
  g[f] = s / (float)n;
  __syncthreads();
  if (f < 64) {
    float z = bg[f];
    #pragma unroll 4
    for (int k = 0; k < NF; k++) z += g[k] * Wg[k * 64 + f];
    out[f] = 1.0f / (1.0f + expf(-z));
  }
}

// ---------------- launch ----------------
extern "C" void kernel_launch(void* const* d_in, const int* in_sizes, int n_in,
                              void* d_out, int out_size, void* d_ws, size_t ws_size,
                              hipStream_t stream) {
  const float* x   = (const float*)d_in[0];
  const int*   ei  = (const int*)d_in[1];
  const float* Wl1 = (const float*)d_in[2];
  const float* Wr1 = (const float*)d_in[3];
  const float* b1  = (const float*)d_in[4];
  const float* Wl2 = (const float*)d_in[5];
  const float* Wr2 = (const float*)d_in[6];
  const float* b2  = (const float*)d_in[7];
  const float* Wl3 = (const float*)d_in[8];
  const float* Wr3 = (const float*)d_in[9];
  const float* b3  = (const float*)d_in[10];
  const float* Wg  = (const float*)d_in[11];
  const float* bg  = (const float*)d_in[12];
  float* out = (float*)d_out;

  int n = in_sizes[0] / NF;      // 100000
  int E = in_sizes[1] / 2;       // 1600000
  const int* srcp = ei;
  const int* dstp = ei + E;

  char* w = (char*)d_ws;
  size_t off = 0;
  auto carve = [&](size_t bytes) -> void* {
    off = (off + 255) & ~(size_t)255;
    void* p = w + off;
    off += bytes;
    return p;
  };
  int nbkt  = (n + PART_NODES - 1) / PART_NODES;   // 196 coarse buckets
  int npart = (E + PART_CHUNK - 1) / PART_CHUNK;   // 391 chunks
  int*    col       = (int*)   carve((size_t)E * 4);
  int*    row_start = (int*)   carve((size_t)(n + 1) * 4);
  int*    bucket_start = (int*)carve((size_t)257 * 4);
  int*    btot      = (int*)   carve((size_t)256 * 4);
  int*    bcnt      = (int*)   carve((size_t)npart * 256 * 4);
  int*    cbase     = (int*)   carve((size_t)npart * 256 * 4);
  ushort* Wtg       = (ushort*)carve((size_t)3 * NF * 256 * 2);
  ushort* xb        = (ushort*)carve((size_t)n * NF * 2);
  uchar*  x8        = (uchar*) carve((size_t)n * NF);
  uchar*  h8        = (uchar*) carve((size_t)n * NF);
  ushort* aggr      = (ushort*)carve((size_t)n * NF * 2);
  ushort* ha        = (ushort*)carve((size_t)n * NF * 2);
  ushort* hb        = (ushort*)carve((size_t)n * NF * 2);
  float*  partial   = (float*) carve((size_t)PB * NF * 4);
  uint*   bkt       = (uint*)hb;   // 4B-packed staging aliases hb (dead until layer 2)

  int ag = (n + 3) / 4;
  int nslab = (n + 63) / 64;

  // convert x to bf16 + fp8; prep transposed bf16 weights
  k_cvt<<<2048, 256, 0, stream>>>(x, xb, x8, n * NF / 4);
  k_wprep<<<3 * NF, 256, 0, stream>>>(Wl1, Wr1, Wl2, Wr2, Wl3, Wr3, Wtg);

  // CSR build: chunk-histogram -> parallel 2D scan -> reserved scatter -> bucket-local fill
  k_part1<<<npart, 256, 0, stream>>>(dstp, bcnt, E);
  k_bscan1<<<256, 256, 0, stream>>>(bcnt, cbase, btot, npart);
  k_bscan2<<<1, 256, 0, stream>>>(btot, bucket_start, row_start, n, E);
  k_part2<<<npart, 256, 0, stream>>>(srcp, dstp, cbase, bucket_start, bkt, E);
  k_fill4<<<nbkt, 256, 0, stream>>>(bkt, bucket_start, row_start, col, n);

  // layer 1: x -> ha  (gather from x8)
  k_aggr_bf<<<ag, 256, 0, stream>>>(x8, row_start, col, aggr, n);
  k_gemm_mfma<<<GEMM_BLOCKS, 256, 0, stream>>>(aggr, xb, ha, h8, Wtg,            b1, n, nslab);
  // layer 2: ha -> hb  (gather from h8 = fp8(ha))
  k_aggr_bf<<<ag, 256, 0, stream>>>(h8, row_start, col, aggr, n);
  k_gemm_mfma<<<GEMM_BLOCKS, 256, 0, stream>>>(aggr, ha, hb, h8, Wtg + NF * 256, b2, n, nslab);
  // layer 3: hb -> ha  (gather from h8 = fp8(hb))
  k_aggr_bf<<<ag, 256, 0, stream>>>(h8, row_start, col, aggr, n);
  k_gemm_mfma<<<GEMM_BLOCKS, 256, 0, stream>>>(aggr, hb, ha, h8, Wtg + 2 * NF * 256, b3, n, nslab);

  // pool + head
  k_pool1<<<PB, 128, 0, stream>>>(ha, partial, n);
  k_pool2<<<1, 128, 0, stream>>>(partial, Wg, bg, out, n);
}

// Round 13
// 447.739 us; speedup vs baseline: 1.1376x; 1.0835x over previous
//
#include <hip/hip_runtime.h>
#include <hip/hip_bf16.h>

#define NF 128   // feature dim
#define PB 512   // pool partial blocks
#define GEMM_BLOCKS 512  // persistent-ish gemm grid
#define PART_SHIFT 9     // 512 nodes per coarse bucket
#define PART_NODES 512
#define PART_CHUNK 4096  // edges per partition block (256 thr x 16)

typedef __attribute__((ext_vector_type(8))) short bf16x8;
typedef __attribute__((ext_vector_type(4))) float f32x4;
typedef __attribute__((ext_vector_type(2))) float f32x2;

__device__ inline float b2f(ushort u) { return __uint_as_float(((uint)u) << 16); }
__device__ inline ushort f2bf(float f) {           // round-to-nearest-even
  uint u = __float_as_uint(f);
  return (ushort)((u + 0x7fffu + ((u >> 16) & 1u)) >> 16);
}
__device__ inline float blo(uint u) { return __uint_as_float(u << 16); }
__device__ inline float bhi(uint u) { return __uint_as_float(u & 0xffff0000u); }

// fp8 e4m3 (OCP) pack via HW converts
__device__ inline uint pk8(float a, float b) {     // 2 floats -> 2 fp8 bytes [b:a]
  return (uint)__builtin_amdgcn_cvt_pk_fp8_f32(a, b, 0, false);
}

// ---------------- x -> bf16 + fp8 ----------------
__global__ __launch_bounds__(256) void k_cvt(const float* __restrict__ x,
                                             ushort* __restrict__ xb,
                                             uchar* __restrict__ x8, int total4) {
  for (int i = blockIdx.x * 256 + threadIdx.x; i < total4; i += gridDim.x * 256) {
    float4 v = *(const float4*)&x[(size_t)i * 4];
    ushort4 o;
    o.x = f2bf(v.x); o.y = f2bf(v.y); o.z = f2bf(v.z); o.w = f2bf(v.w);
    *(ushort4*)&xb[(size_t)i * 4] = o;
    int p = __builtin_amdgcn_cvt_pk_fp8_f32(v.x, v.y, 0, false);
    p = __builtin_amdgcn_cvt_pk_fp8_f32(v.z, v.w, p, true);
    *(uint*)&x8[(size_t)i * 4] = (uint)p;
  }
}

// ---------------- weight prep: [k][c] f32 x2 -> [c][k 0..255] bf16 ----------------
__global__ __launch_bounds__(256) void k_wprep(const float* __restrict__ Wl1,
                                               const float* __restrict__ Wr1,
                                               const float* __restrict__ Wl2,
                                               const float* __restrict__ Wr2,
                                               const float* __restrict__ Wl3,
                                               const float* __restrict__ Wr3,
                                               ushort* __restrict__ Wtg) {
  int l = blockIdx.x >> 7;          // layer 0..2
  int c = blockIdx.x & 127;         // col
  int k = threadIdx.x;              // 0..255
  const float* Wl = (l == 0) ? Wl1 : (l == 1) ? Wl2 : Wl3;
  const float* Wr = (l == 0) ? Wr1 : (l == 1) ? Wr2 : Wr3;
  float v = (k < 128) ? Wl[k * NF + c] : Wr[(k - 128) * NF + c];
  Wtg[((size_t)l * NF + c) * 256 + k] = f2bf(v);
}

// ---------------- CSR build (atomic-free, chunk x bucket) ----------------
__global__ __launch_bounds__(256) void k_part1(const int* __restrict__ dst,
                                               int* __restrict__ bcnt, int E) {
  __shared__ int lhist[256];
  int t = threadIdx.x;
  int cb = blockIdx.x * PART_CHUNK;
  lhist[t] = 0;
  __syncthreads();
  #pragma unroll
  for (int i = 0; i < 16; i++) {
    int e = cb + i * 256 + t;
    if (e < E) atomicAdd(&lhist[dst[e] >> PART_SHIFT], 1);
  }
  __syncthreads();
  bcnt[blockIdx.x * 256 + t] = lhist[t];
}

// per-bucket column scan over chunks (256 blocks, parallel)
__global__ __launch_bounds__(256) void k_bscan1(const int* __restrict__ bcnt,
                                                int* __restrict__ cbase,
                                                int* __restrict__ btot, int npart) {
  __shared__ int s[256];
  int b = blockIdx.x;   // bucket
  int t = threadIdx.x;
  int base = 0;
  for (int seg = 0; seg * 256 < npart; seg++) {
    int c = seg * 256 + t;
    int v = (c < npart) ? bcnt[c * 256 + b] : 0;
    s[t] = v;
    __syncthreads();
    for (int off = 1; off < 256; off <<= 1) {
      int u = (t >= off) ? s[t - off] : 0;
      __syncthreads();
      s[t] += u;
      __syncthreads();
    }
    if (c < npart) cbase[c * 256 + b] = base + s[t] - v;  // chunk-exclusive, no bucket base
    base += s[255];
    __syncthreads();
  }
  if (t == 0) btot[b] = base;
}

// 1 block: bucket_start[0..256], row_start[n]=E
__global__ __launch_bounds__(256) void k_bscan2(const int* __restrict__ btot,
                                                int* __restrict__ bucket_start,
                                                int* __restrict__ row_start,
                                                int n, int E) {
  __shared__ int s[256];
  int t = threadIdx.x;
  int v = btot[t];
  s[t] = v;
  __syncthreads();
  for (int off = 1; off < 256; off <<= 1) {
    int u = (t >= off) ? s[t - off] : 0;
    __syncthreads();
    s[t] += u;
    __syncthreads();
  }
  bucket_start[t] = s[t] - v;            // exclusive prefix
  if (t == 255) bucket_start[256] = s[255];   // = E
  if (t == 0) row_start[n] = E;
}

// LDS-ranked scatter into reserved runs (no global atomics)
__global__ __launch_bounds__(256) void k_part2(const int* __restrict__ src,
                                               const int* __restrict__ dst,
                                               const int* __restrict__ cbase,
                                               const int* __restrict__ bucket_start,
                                               uint* __restrict__ bkt, int E) {
  __shared__ int lhist[256];
  __shared__ int lbase[256];
  int t = threadIdx.x;
  int cb = blockIdx.x * PART_CHUNK;
  lhist[t] = 0;
  __syncthreads();
  uint rec[16];
  short rb[16];
  short rr[16];
  #pragma unroll
  for (int i = 0; i < 16; i++) {
    int e = cb + i * 256 + t;
    if (e < E) {
      int s = src[e], d = dst[e];
      int b = d >> PART_SHIFT;
      rec[i] = ((uint)(d & (PART_NODES - 1)) << 17) | (uint)s;
      rb[i] = (short)b;
      rr[i] = (short)atomicAdd(&lhist[b], 1);
    } else rb[i] = -1;
  }
  __syncthreads();
  lbase[t] = cbase[blockIdx.x * 256 + t] + bucket_start[t];
  __syncthreads();
  #pragma unroll
  for (int i = 0; i < 16; i++) {
    if (rb[i] >= 0) bkt[lbase[rb[i]] + (int)rr[i]] = rec[i];
  }
}

// one block per bucket; LDS degree count + scan -> row_start + place col
__global__ __launch_bounds__(256) void k_fill4(const uint* __restrict__ bkt,
                                               const int* __restrict__ bucket_start,
                                               int* __restrict__ row_start,
                                               int* __restrict__ col, int n) {
  __shared__ int dcnt[PART_NODES];
  __shared__ int s[256];
  __shared__ int cur[PART_NODES];
  int t = threadIdx.x;
  int base = blockIdx.x << PART_SHIFT;
  dcnt[2 * t] = 0; dcnt[2 * t + 1] = 0;
  __syncthreads();
  int ebeg = bucket_start[blockIdx.x], eend = bucket_start[blockIdx.x + 1];
  for (int j = ebeg + t; j < eend; j += 256)
    atomicAdd(&dcnt[bkt[j] >> 17], 1);
  __syncthreads();
  int d0 = dcnt[2 * t], d1 = dcnt[2 * t + 1];
  int pair = d0 + d1;
  s[t] = pair;
  __syncthreads();
  for (int off = 1; off < 256; off <<= 1) {
    int u = (t >= off) ? s[t - off] : 0;
    __syncthreads();
    s[t] += u;
    __syncthreads();
  }
  int pre = ebeg + s[t] - pair;      // exclusive within bucket
  cur[2 * t] = pre;
  cur[2 * t + 1] = pre + d0;
  if (base + 2 * t < n)     row_start[base + 2 * t]     = pre;
  if (base + 2 * t + 1 < n) row_start[base + 2 * t + 1] = pre + d0;
  __syncthreads();
  for (int j = ebeg + t; j < eend; j += 256) {
    uint r = bkt[j];
    int pos = atomicAdd(&cur[r >> 17], 1);
    col[pos] = (int)(r & 0x1FFFFu);
  }
}

// ---------------- gather-mean (fp8 in, bf16 out, fp32 accum) ----------------
__global__ __launch_bounds__(256) void k_aggr_bf(const uchar* __restrict__ h8,
                                                 const int* __restrict__ row_start,
                                                 const int* __restrict__ col,
                                                 ushort* __restrict__ aggr, int n) {
  int gw = (blockIdx.x * 256 + threadIdx.x) >> 6;
  int lane = threadIdx.x & 63;
  if (gw >= n) return;
  int beg = row_start[gw], end = row_start[gw + 1];
  int q = lane >> 4, sl = lane & 15;
  const uchar* hbase = h8 + (size_t)sl * 8;
  float a[8];
  #pragma unroll
  for (int i = 0; i < 8; i++) a[i] = 0.f;

  for (int cb = beg; cb < end; cb += 64) {
    int idx = cb + lane;
    int cv = (idx < end) ? col[idx] : 0;
    int m = min(64, end - cb);
    int j = 0;
    for (; j + 16 <= m; j += 16) {       // 4 quads (16 edges) in flight
      int s0 = __shfl(cv, j + q);
      int s1 = __shfl(cv, j + 4 + q);
      int s2 = __shfl(cv, j + 8 + q);
      int s3 = __shfl(cv, j + 12 + q);
      uint2 v0 = *(const uint2*)&hbase[(size_t)s0 * NF];
      uint2 v1 = *(const uint2*)&hbase[(size_t)s1 * NF];
      uint2 v2 = *(const uint2*)&hbase[(size_t)s2 * NF];
      uint2 v3 = *(const uint2*)&hbase[(size_t)s3 * NF];
      #pragma unroll
      for (int k = 0; k < 4; k++) {
        uint2 v = (k == 0) ? v0 : (k == 1) ? v1 : (k == 2) ? v2 : v3;
        f32x2 f0 = __builtin_amdgcn_cvt_pk_f32_fp8((int)v.x, false);
        f32x2 f1 = __builtin_amdgcn_cvt_pk_f32_fp8((int)v.x, true);
        f32x2 f2 = __builtin_amdgcn_cvt_pk_f32_fp8((int)v.y, false);
        f32x2 f3 = __builtin_amdgcn_cvt_pk_f32_fp8((int)v.y, true);
        a[0] += f0.x; a[1] += f0.y; a[2] += f1.x; a[3] += f1.y;
        a[4] += f2.x; a[5] += f2.y; a[6] += f3.x; a[7] += f3.y;
      }
    }
    for (; j < m; j += 4) {              // tail quads (possibly partial)
      int e = j + q;
      int s = __shfl(cv, (e < m) ? e : 0);
      if (e < m) {
        uint2 v = *(const uint2*)&hbase[(size_t)s * NF];
        f32x2 f0 = __builtin_amdgcn_cvt_pk_f32_fp8((int)v.x, false);
        f32x2 f1 = __builtin_amdgcn_cvt_pk_f32_fp8((int)v.x, true);
        f32x2 f2 = __builtin_amdgcn_cvt_pk_f32_fp8((int)v.y, false);
        f32x2 f3 = __builtin_amdgcn_cvt_pk_f32_fp8((int)v.y, true);
        a[0] += f0.x; a[1] += f0.y; a[2] += f1.x; a[3] += f1.y;
        a[4] += f2.x; a[5] += f2.y; a[6] += f3.x; a[7] += f3.y;
      }
    }
  }
  #pragma unroll
  for (int i = 0; i < 8; i++) {
    a[i] += __shfl_xor(a[i], 16);
    a[i] += __shfl_xor(a[i], 32);
  }
  int d = end - beg;
  float inv = (d > 0) ? 1.0f / (float)d : 0.0f;
  if (q == 0) {
    uint4 o;
    o.x = (uint)f2bf(a[0] * inv) | ((uint)f2bf(a[1] * inv) << 16);
    o.y = (uint)f2bf(a[2] * inv) | ((uint)f2bf(a[3] * inv) << 16);
    o.z = (uint)f2bf(a[4] * inv) | ((uint)f2bf(a[5] * inv) << 16);
    o.w = (uint)f2bf(a[6] * inv) | ((uint)f2bf(a[7] * inv) << 16);
    *(uint4*)&aggr[(size_t)gw * NF + sl * 8] = o;
  }
}

// ---------------- MFMA GEMM (no LDS): hout = relu([aggr|hin] @ Wtg_l + b) ----------------
// also emits fp8 shadow copy h8out for the next layer's gather.
__global__ __launch_bounds__(256) void k_gemm_mfma(const ushort* __restrict__ aggr,
                                                   const ushort* __restrict__ hin,
                                                   ushort* __restrict__ hout,
                                                   uchar* __restrict__ h8out,
                                                   const ushort* __restrict__ Wtg,
                                                   const float* __restrict__ bias,
                                                   int n, int nslab) {
  int t = threadIdx.x;
  int wv = t >> 6, lane = t & 63;
  int c0 = wv * 32;
  int lrow = lane & 15, lhi = lane >> 4;

  // lane holds B[k = kc*32 + lhi*8 + j][col = c0 + ct*16 + lrow]
  bf16x8 bfrag[8][2];
  #pragma unroll
  for (int kc = 0; kc < 8; kc++)
    #pragma unroll
    for (int ct = 0; ct < 2; ct++) {
      int colv = c0 + ct * 16 + lrow;
      bfrag[kc][ct] = *(const bf16x8*)&Wtg[(size_t)colv * 256 + kc * 32 + lhi * 8];
    }
  float bv0 = bias[c0 + lrow], bv1 = bias[c0 + 16 + lrow];

  for (int sl = blockIdx.x; sl < nslab; sl += GEMM_BLOCKS) {
    int row0 = sl * 64;
    f32x4 acc[4][2];
    #pragma unroll
    for (int rt = 0; rt < 4; rt++)
      #pragma unroll
      for (int ct = 0; ct < 2; ct++) acc[rt][ct] = (f32x4){0.f, 0.f, 0.f, 0.f};

    #pragma unroll
    for (int kc = 0; kc < 8; kc++) {
      const ushort* Asrc = (kc < 4) ? aggr : hin;
      int k0 = (kc & 3) * 32 + lhi * 8;
      bf16x8 af[4];
      #pragma unroll
      for (int rt = 0; rt < 4; rt++) {
        int r = row0 + rt * 16 + lrow;
        if (r >= n) r = n - 1;
        af[rt] = *(const bf16x8*)&Asrc[(size_t)r * NF + k0];
      }
      #pragma unroll
      for (int rt = 0; rt < 4; rt++) {
        acc[rt][0] = __builtin_amdgcn_mfma_f32_16x16x32_bf16(af[rt], bfrag[kc][0], acc[rt][0], 0, 0, 0);
        acc[rt][1] = __builtin_amdgcn_mfma_f32_16x16x32_bf16(af[rt], bfrag[kc][1], acc[rt][1], 0, 0, 0);
      }
    }
    // C/D: col = lane&15, row = (lane>>4)*4 + reg   [m89-verified]
    #pragma unroll
    for (int rt = 0; rt < 4; rt++) {
      int rbase = row0 + rt * 16 + lhi * 4;
      #pragma unroll
      for (int r = 0; r < 4; r++) {
        int row = rbase + r;
        if (row < n) {
          float o0 = fmaxf(acc[rt][0][r] + bv0, 0.f);
          float o1 = fmaxf(acc[rt][1][r] + bv1, 0.f);
          hout[(size_t)row * NF + c0 + lrow]      = f2bf(o0);
          hout[(size_t)row * NF + c0 + 16 + lrow] = f2bf(o1);
          uint p = pk8(o0, o1);
          h8out[(size_t)row * NF + c0 + lrow]      = (uchar)(p & 0xff);
          h8out[(size_t)row * NF + c0 + 16 + lrow] = (uchar)((p >> 8) & 0xff);
        }
      }
    }
  }
}

// ---------------- pool + head ----------------
// vectorized: cg = t&15 owns feats [cg*8, cg*8+8); wave load = 4 rows x 256B
__global__ __launch_bounds__(256) void k_pool1(const ushort* __restrict__ h,
                                               float* __restrict__ partial, int n) {
  __shared__ float s[256 * 9];       // *9 pad to break reduce-phase conflicts
  int t = threadIdx.x;
  int cg = t & 15;
  float a[8];
  #pragma unroll
  for (int i = 0; i < 8; i++) a[i] = 0.f;
  for (int r = blockIdx.x * 16 + (t >> 4); r < n; r += PB * 16) {
    uint4 v = *(const uint4*)&h[(size_t)r * NF + cg * 8];
    a[0] += blo(v.x); a[1] += bhi(v.x);
    a[2] += blo(v.y); a[3] += bhi(v.y);
    a[4] += blo(v.z); a[5] += bhi(v.z);
    a[6] += blo(v.w); a[7] += bhi(v.w);
  }
  #pragma unroll
  for (int i = 0; i < 8; i++) s[t * 9 + i] = a[i];
  __syncthreads();
  if (t < 16) {
    float acc[8];
    #pragma unroll
    for (int i = 0; i < 8; i++) acc[i] = 0.f;
    for (int j = 0; j < 16; j++)
      #pragma unroll
      for (int i = 0; i < 8; i++) acc[i] += s[(j * 16 + t) * 9 + i];
    #pragma unroll
    for (int i = 0; i < 8; i++) partial[blockIdx.x * NF + t * 8 + i] = acc[i];
  }
}

__global__ __launch_bounds__(128) void k_pool2(const float* __restrict__ partial,
                                               const float* __restrict__ Wg,
                                               const float* __restrict__ bg,
                                               float* __restrict__ out, int n) {
  __shared__ float g[NF];
  int f = threadIdx.x;
  float s = 0.f;
  for (int b = 0; b < PB; b++) s += partial[b * NF + f];
  g[f] = s / (float)n;
  __syncthreads();
  if (f < 64) {
    float z = bg[f];
    #pragma unroll 4
    for (int k = 0; k < NF; k++) z += g[k] * Wg[k * 64 + f];
    out[f] = 1.0f / (1.0f + expf(-z));
  }
}

// ---------------- launch ----------------
extern "C" void kernel_launch(void* const* d_in, const int* in_sizes, int n_in,
                              void* d_out, int out_size, void* d_ws, size_t ws_size,
                              hipStream_t stream) {
  const float* x   = (const float*)d_in[0];
  const int*   ei  = (const int*)d_in[1];
  const float* Wl1 = (const float*)d_in[2];
  const float* Wr1 = (const float*)d_in[3];
  const float* b1  = (const float*)d_in[4];
  const float* Wl2 = (const float*)d_in[5];
  const float* Wr2 = (const float*)d_in[6];
  const float* b2  = (const float*)d_in[7];
  const float* Wl3 = (const float*)d_in[8];
  const float* Wr3 = (const float*)d_in[9];
  const float* b3  = (const float*)d_in[10];
  const float* Wg  = (const float*)d_in[11];
  const float* bg  = (const float*)d_in[12];
  float* out = (float*)d_out;

  int n = in_sizes[0] / NF;      // 100000
  int E = in_sizes[1] / 2;       // 1600000
  const int* srcp = ei;
  const int* dstp = ei + E;

  char* w = (char*)d_ws;
  size_t off = 0;
  auto carve = [&](size_t bytes) -> void* {
    off = (off + 255) & ~(size_t)255;
    void* p = w + off;
    off += bytes;
    return p;
  };
  int nbkt  = (n + PART_NODES - 1) / PART_NODES;   // 196 coarse buckets
  int npart = (E + PART_CHUNK - 1) / PART_CHUNK;   // 391 chunks
  int*    col       = (int*)   carve((size_t)E * 4);
  int*    row_start = (int*)   carve((size_t)(n + 1) * 4);
  int*    bucket_start = (int*)carve((size_t)257 * 4);
  int*    btot      = (int*)   carve((size_t)256 * 4);
  int*    bcnt      = (int*)   carve((size_t)npart * 256 * 4);
  int*    cbase     = (int*)   carve((size_t)npart * 256 * 4);
  ushort* Wtg       = (ushort*)carve((size_t)3 * NF * 256 * 2);
  ushort* xb        = (ushort*)carve((size_t)n * NF * 2);
  uchar*  x8        = (uchar*) carve((size_t)n * NF);
  uchar*  h8        = (uchar*) carve((size_t)n * NF);
  ushort* aggr      = (ushort*)carve((size_t)n * NF * 2);
  ushort* ha        = (ushort*)carve((size_t)n * NF * 2);
  ushort* hb        = (ushort*)carve((size_t)n * NF * 2);
  float*  partial   = (float*) carve((size_t)PB * NF * 4);
  uint*   bkt       = (uint*)hb;   // 4B-packed staging aliases hb (dead until layer 2)

  int ag = (n + 3) / 4;
  int nslab = (n + 63) / 64;

  // convert x to bf16 + fp8; prep transposed bf16 weights
  k_cvt<<<2048, 256, 0, stream>>>(x, xb, x8, n * NF / 4);
  k_wprep<<<3 * NF, 256, 0, stream>>>(Wl1, Wr1, Wl2, Wr2, Wl3, Wr3, Wtg);

  // CSR build: chunk-histogram -> parallel 2D scan -> reserved scatter -> bucket-local fill
  k_part1<<<npart, 256, 0, stream>>>(dstp, bcnt, E);
  k_bscan1<<<256, 256, 0, stream>>>(bcnt, cbase, btot, npart);
  k_bscan2<<<1, 256, 0, stream>>>(btot, bucket_start, row_start, n, E);
  k_part2<<<npart, 256, 0, stream>>>(srcp, dstp, cbase, bucket_start, bkt, E);
  k_fill4<<<nbkt, 256, 0, stream>>>(bkt, bucket_start, row_start, col, n);

  // layer 1: x -> ha  (gather from x8)
  k_aggr_bf<<<ag, 256, 0, stream>>>(x8, row_start, col, aggr, n);
  k_gemm_mfma<<<GEMM_BLOCKS, 256, 0, stream>>>(aggr, xb, ha, h8, Wtg,            b1, n, nslab);
  // layer 2: ha -> hb  (gather from h8 = fp8(ha))
  k_aggr_bf<<<ag, 256, 0, stream>>>(h8, row_start, col, aggr, n);
  k_gemm_mfma<<<GEMM_BLOCKS, 256, 0, stream>>>(aggr, ha, hb, h8, Wtg + NF * 256, b2, n, nslab);
  // layer 3: hb -> ha  (gather from h8 = fp8(hb))
  k_aggr_bf<<<ag, 256, 0, stream>>>(h8, row_start, col, aggr, n);
  k_gemm_mfma<<<GEMM_BLOCKS, 256, 0, stream>>>(aggr, hb, ha, h8, Wtg + 2 * NF * 256, b3, n, nslab);

  // pool + head
  k_pool1<<<PB, 256, 0, stream>>>(ha, partial, n);
  k_pool2<<<1, 128, 0, stream>>>(partial, Wg, bg, out, n);
}